// Round 7
// baseline (58.510 us; speedup 1.0000x reference)
//
#include <hip/hip_runtime.h>

// RankingBCELoss: loss = (1/(n_pos*n_neg)) * sum_{p,n} log(1 + e^{x_n} * e^{-x_p})
// R7 = compaction (R3's kernel, verified) + register-tiled pair kernel (R6's
// inner loop, verified), so pair work covers only REAL pairs (~67M, not 268M).
//   K1: single block compacts to pos_emp[np] (e^{-x_pos}), neg_en[nn_pad]
//       (e^{x_neg}, zero-padded to x4096; pad terms fma(0,emp,1)=1 -> log2=0),
//       writes cnts{np,nn,nn_pad}, resets arrival counter.
//   K2: block = 32 rows x (nn_pad/4) cols. emp[32] in VGPRs (static indices
//       only); 1 ds_read_b128 feeds 4 cols x 32 rows = 128 fma + 112 mul +
//       16 v_log_f32. Grid 512x4=2048, blocks with rbase>=np exit (uniform).
//       Last-arriving block (ACQ_REL agent scope) reduces partials + finalizes.

#define CB   1024          // compact kernel threads (single block)
#define PT   256           // pair kernel threads
#define RB   32            // rows per pair block
#define NCQ  4             // column quarters
#define QMAX 4096          // max floats per col-quarter (16 KB LDS)

// ---- Kernel 1: compaction + exp precompute (single block, coalesced) ------
__global__ __launch_bounds__(CB)
void compact_kernel(const float* __restrict__ x, const int* __restrict__ tg,
                    int n, float* __restrict__ pos_emp, float* __restrict__ neg_en,
                    int* __restrict__ cnts, unsigned int* __restrict__ done) {
    __shared__ float sbuf[16384];       // pos from front, neg from back
    __shared__ int swsum[16], swoff[16], stot;
    const int tid  = threadIdx.x;
    const int lane = tid & 63, wid = tid >> 6;
    const int n4 = n >> 2;              // n == 16384: 4096 float4s, 4 per thread

    float4 vf[4]; int4 vt[4];
    int lp = 0, ln = 0;
#pragma unroll
    for (int k = 0; k < 4; ++k) {
        const int i4 = tid + k * CB;
        if (i4 < n4) { vf[k] = ((const float4*)x)[i4]; vt[k] = ((const int4*)tg)[i4]; }
        else         { vf[k] = make_float4(0,0,0,0); vt[k] = make_int4(-1,-1,-1,-1); }
        lp += (vt[k].x==1) + (vt[k].y==1) + (vt[k].z==1) + (vt[k].w==1);
        ln += (vt[k].x==0) + (vt[k].y==0) + (vt[k].z==0) + (vt[k].w==0);
    }

    // packed (pos | neg<<16) inclusive wave scan, then cross-wave scan
    const int c = lp | (ln << 16);
    int inc = c;
#pragma unroll
    for (int off = 1; off < 64; off <<= 1) {
        int u = __shfl_up(inc, off, 64);
        if (lane >= off) inc += u;
    }
    if (lane == 63) swsum[wid] = inc;
    __syncthreads();
    if (tid < 16) {
        int val = swsum[tid];
        int sc = val;
#pragma unroll
        for (int off = 1; off < 16; off <<= 1) {
            int u = __shfl_up(sc, off, 64);
            if (tid >= off) sc += u;
        }
        swoff[tid] = sc - val;          // exclusive wave offset
        if (tid == 15) stot = sc;       // packed totals
    }
    __syncthreads();
    const int ex = swoff[wid] + (inc - c);   // exclusive thread prefix (packed)
    int op = ex & 0xffff;
    int on = ex >> 16;
#pragma unroll
    for (int k = 0; k < 4; ++k) {
        const float vx[4] = {vf[k].x, vf[k].y, vf[k].z, vf[k].w};
        const int   tx[4] = {vt[k].x, vt[k].y, vt[k].z, vt[k].w};
#pragma unroll
        for (int j = 0; j < 4; ++j) {
            if (tx[j] == 1)      sbuf[op++]           = __expf(-vx[j]);  // e^{-x_pos}
            else if (tx[j] == 0) sbuf[n - 1 - (on++)] = __expf(vx[j]);   // e^{x_neg}
        }
    }
    __syncthreads();
    const int np = stot & 0xffff;
    const int nn = stot >> 16;
    const int nn_pad = (nn + (QMAX - 1)) & ~(QMAX - 1);   // x4096 (quarters x1024)
    for (int i = tid; i < np; i += CB)          pos_emp[i] = sbuf[i];
    for (int i = tid; i < nn; i += CB)          neg_en[i]  = sbuf[n - 1 - i];
    for (int i = nn + tid; i < nn_pad; i += CB) neg_en[i]  = 0.f;
    if (tid == 0) { cnts[0] = np; cnts[1] = nn; cnts[2] = nn_pad; *done = 0u; }
}

// ---- Kernel 2: register-tiled pairs over compacted arrays -----------------
__global__ __launch_bounds__(PT)
void pair_kernel(const float* __restrict__ pos_emp, const float* __restrict__ neg_en,
                 const int* __restrict__ cnts, double* __restrict__ partials,
                 unsigned int* __restrict__ done, float* __restrict__ out) {
    __shared__ float lds[QMAX];              // 16 KB staged en quarter
    __shared__ double wsum[PT / 64], fsum[PT / 64];
    __shared__ int amFlag;
    const int bid = blockIdx.x, tid = threadIdx.x;
    const int nblocks = (int)gridDim.x;
    const int np = cnts[0], nn_pad = cnts[2];
    const int quarter = nn_pad >> 2;         // multiple of 1024 floats
    const int rowblk = bid >> 2, colq = bid & (NCQ - 1);
    const int rbase = rowblk * RB;
    const bool active = (rbase < np) && (quarter > 0);   // block-uniform

    float acc0 = 0.f, acc1 = 0.f, acc2 = 0.f, acc3 = 0.f;
    if (active) {
        const int qf4 = quarter >> 2;        // float4s this quarter (<=1024)
        const float4* src4 = (const float4*)(neg_en + colq * quarter);
        for (int vi = tid; vi < qf4; vi += PT) ((float4*)lds)[vi] = src4[vi];

        float emp[RB];                       // static-indexed only => registers
#pragma unroll
        for (int r = 0; r < RB; ++r) {
            const int row = rbase + r;
            emp[r] = (row < np) ? pos_emp[row] : 0.f;   // OOR row contributes 0
        }
        __syncthreads();

#define TERM(EN, R)  __builtin_fmaf((EN), emp[R], 1.0f)
#define Q4(EN, R0)   (((TERM(EN,R0) * TERM(EN,(R0)+1)) * TERM(EN,(R0)+2)) * TERM(EN,(R0)+3))
        // terms in [1, ~5e3]; product of 8 <= ~1.5e29 < 3.4e38: safe
#define DO_COL(EN)                                          \
        do {                                                \
            const float en_ = (EN);                         \
            acc0 += __log2f(Q4(en_, 0)  * Q4(en_, 4));      \
            acc1 += __log2f(Q4(en_, 8)  * Q4(en_, 12));     \
            acc2 += __log2f(Q4(en_, 16) * Q4(en_, 20));     \
            acc3 += __log2f(Q4(en_, 24) * Q4(en_, 28));     \
        } while (0)

#pragma unroll 2
        for (int cb = 0; cb < qf4; cb += PT) {
            const float4 e4 = ((const float4*)lds)[cb + tid];
            DO_COL(e4.x);
            DO_COL(e4.y);
            DO_COL(e4.z);
            DO_COL(e4.w);
        }
#undef DO_COL
#undef Q4
#undef TERM
    }

    // ---- block reduction -> partials[bid]; arrival; last block finalizes ----
    float s = (acc0 + acc1) + (acc2 + acc3);
#pragma unroll
    for (int off = 32; off > 0; off >>= 1) s += __shfl_down(s, off, 64);
    if ((tid & 63) == 0) wsum[tid >> 6] = (double)s;
    __syncthreads();
    if (tid == 0) {
        double b = 0.0;
#pragma unroll
        for (int w = 0; w < PT / 64; ++w) b += wsum[w];
        partials[bid] = b;
        // ACQ_REL agent-scope arrival: releases our store; winning RMW acquires all.
        const unsigned old = __hip_atomic_fetch_add(done, 1u, __ATOMIC_ACQ_REL,
                                                    __HIP_MEMORY_SCOPE_AGENT);
        amFlag = (old == (unsigned)(nblocks - 1)) ? 1 : 0;
    }
    __syncthreads();

    if (amFlag) {                            // last arriving block (any block works)
        double d = 0.0;
        for (int k = tid; k < nblocks; k += PT) d += partials[k];  // fixed order
#pragma unroll
        for (int off = 32; off > 0; off >>= 1) d += __shfl_down(d, off, 64);
        if ((tid & 63) == 0) fsum[tid >> 6] = d;
        __syncthreads();
        if (tid == 0) {
            double ssum = 0.0;
#pragma unroll
            for (int w = 0; w < PT / 64; ++w) ssum += fsum[w];
            const double npairs = (double)cnts[0] * (double)cnts[1];
            out[0] = (npairs > 0.0) ? (float)(ssum * 0.6931471805599453 / npairs) : 0.0f;
        }
    }
}

extern "C" void kernel_launch(void* const* d_in, const int* in_sizes, int n_in,
                              void* d_out, int out_size, void* d_ws, size_t ws_size,
                              hipStream_t stream) {
    const float* x  = (const float*)d_in[0];
    const int*   tg = (const int*)d_in[1];
    const int n = in_sizes[0];                 // 16384

    char* ws = (char*)d_ws;
    float*        pos_emp  = (float*)(ws);             // 64 KB
    float*        neg_en   = (float*)(ws + 65536);     // 64 KB (incl. zero pad)
    int*          cnts     = (int*)(ws + 131072);      // 3 ints
    unsigned int* done     = (unsigned int*)(ws + 131200);
    double*       partials = (double*)(ws + 131328);   // 2048 doubles = 16 KB

    const int rowblks = (n + RB - 1) / RB;     // 512 (worst case: all positive)
    const int nblocks = rowblks * NCQ;         // 2048
    compact_kernel<<<1, CB, 0, stream>>>(x, tg, n, pos_emp, neg_en, cnts, done);
    pair_kernel<<<nblocks, PT, 0, stream>>>(pos_emp, neg_en, cnts, partials, done,
                                            (float*)d_out);
}

// Round 8
// 21.662 us; speedup vs baseline: 2.7010x; 2.7010x over previous
//
#include <hip/hip_runtime.h>

// RankingBCELoss: loss = (1/(n_pos*n_neg)) * sum_{p,n} log(1 + e^{x_n} * e^{-x_p})
// R8: remove ALL device-wide serialization from the hot kernel.
//   K1 compact: single block, coalesced float4 loads, shfl scan ->
//       pos_emp[np]=e^{-x_pos}, neg_en[nn_pad]=e^{x_neg} (zero-pad to x4;
//       pad gives fma(0,emp,1)=1 -> log2=0), cnts{np,nn,nn_pad}.
//   K2 pair: NO LDS, NO __syncthreads, NO atomics. 1024 blocks x 512 thr,
//       RB=16 rows/block; emp[16] in VGPRs (static indices only); each thread
//       streams its own float4 columns of neg_en from global (32KB, L1/L2-hit
//       after first touch; column data has zero intra-block reuse so LDS was
//       pure overhead). Per float4: 4 cols x (16 fma + 14 mul + 2 v_log_f32).
//       Wave-reduce -> wpart[8192] (disjoint doubles).
//   K3 finalize: one block reduces wpart + cnts -> out.

#define CB   1024          // compact kernel threads (single block)
#define PT2  512           // pair kernel threads (8 waves)
#define RB   16            // rows per pair block
#define NW   (PT2 / 64)    // waves per pair block

// ---- Kernel 1: compaction + exp precompute (single block, coalesced) ------
__global__ __launch_bounds__(CB)
void compact_kernel(const float* __restrict__ x, const int* __restrict__ tg,
                    int n, float* __restrict__ pos_emp, float* __restrict__ neg_en,
                    int* __restrict__ cnts) {
    __shared__ float sbuf[16384];       // pos from front, neg from back
    __shared__ int swsum[16], swoff[16], stot;
    const int tid  = threadIdx.x;
    const int lane = tid & 63, wid = tid >> 6;
    const int n4 = n >> 2;              // n == 16384: 4096 float4s, 4 per thread

    float4 vf[4]; int4 vt[4];
    int lp = 0, ln = 0;
#pragma unroll
    for (int k = 0; k < 4; ++k) {
        const int i4 = tid + k * CB;
        if (i4 < n4) { vf[k] = ((const float4*)x)[i4]; vt[k] = ((const int4*)tg)[i4]; }
        else         { vf[k] = make_float4(0,0,0,0); vt[k] = make_int4(-1,-1,-1,-1); }
        lp += (vt[k].x==1) + (vt[k].y==1) + (vt[k].z==1) + (vt[k].w==1);
        ln += (vt[k].x==0) + (vt[k].y==0) + (vt[k].z==0) + (vt[k].w==0);
    }

    // packed (pos | neg<<16) inclusive wave scan, then cross-wave scan
    const int c = lp | (ln << 16);
    int inc = c;
#pragma unroll
    for (int off = 1; off < 64; off <<= 1) {
        int u = __shfl_up(inc, off, 64);
        if (lane >= off) inc += u;
    }
    if (lane == 63) swsum[wid] = inc;
    __syncthreads();
    if (tid < 16) {
        int val = swsum[tid];
        int sc = val;
#pragma unroll
        for (int off = 1; off < 16; off <<= 1) {
            int u = __shfl_up(sc, off, 64);
            if (tid >= off) sc += u;
        }
        swoff[tid] = sc - val;          // exclusive wave offset
        if (tid == 15) stot = sc;       // packed totals
    }
    __syncthreads();
    const int ex = swoff[wid] + (inc - c);   // exclusive thread prefix (packed)
    int op = ex & 0xffff;
    int on = ex >> 16;
#pragma unroll
    for (int k = 0; k < 4; ++k) {
        const float vx[4] = {vf[k].x, vf[k].y, vf[k].z, vf[k].w};
        const int   tx[4] = {vt[k].x, vt[k].y, vt[k].z, vt[k].w};
#pragma unroll
        for (int j = 0; j < 4; ++j) {
            if (tx[j] == 1)      sbuf[op++]           = __expf(-vx[j]);  // e^{-x_pos}
            else if (tx[j] == 0) sbuf[n - 1 - (on++)] = __expf(vx[j]);   // e^{x_neg}
        }
    }
    __syncthreads();
    const int np = stot & 0xffff;
    const int nn = stot >> 16;
    const int nn_pad = (nn + 3) & ~3;   // float4 granularity
    for (int i = tid; i < np; i += CB)          pos_emp[i] = sbuf[i];
    for (int i = tid; i < nn; i += CB)          neg_en[i]  = sbuf[n - 1 - i];
    for (int i = nn + tid; i < nn_pad; i += CB) neg_en[i]  = 0.f;
    if (tid == 0) { cnts[0] = np; cnts[1] = nn; cnts[2] = nn_pad; }
}

// ---- Kernel 2: register-tiled pairs; barrier-free, LDS-free, atomic-free ---
__global__ __launch_bounds__(PT2)
void pair_kernel(const float* __restrict__ pos_emp, const float* __restrict__ neg_en,
                 const int* __restrict__ cnts, double* __restrict__ wpart) {
    const int bid = blockIdx.x, tid = threadIdx.x;
    const int wid = tid >> 6, lane = tid & 63;
    const int gw  = bid * NW + wid;          // global wave index (disjoint slot)
    const int np = cnts[0];
    const int nnpad4 = cnts[2] >> 2;
    const int rbase = bid * RB;

    if (rbase >= np || nnpad4 == 0) {        // block-uniform early out
        if (lane == 0) wpart[gw] = 0.0;
        return;
    }

    float emp[RB];                           // static-indexed only => registers
#pragma unroll
    for (int r = 0; r < RB; ++r) {
        const int row = rbase + r;           // block-uniform address
        emp[r] = (row < np) ? pos_emp[row] : 0.f;   // OOR row contributes 0
    }

    float acc0 = 0.f, acc1 = 0.f;
#define TERM(EN, R)  __builtin_fmaf((EN), emp[R], 1.0f)
#define Q4(EN, R0)   (((TERM(EN,R0) * TERM(EN,(R0)+1)) * TERM(EN,(R0)+2)) * TERM(EN,(R0)+3))
    // terms in [1, ~2e4]; product of 8 <= ~6e34 < 3.4e38: safe
#define DO_COL(EN)                                      \
    do {                                                \
        const float en_ = (EN);                         \
        acc0 += __log2f(Q4(en_, 0) * Q4(en_, 4));       \
        acc1 += __log2f(Q4(en_, 8) * Q4(en_, 12));      \
    } while (0)

    const float4* __restrict__ en4 = (const float4*)neg_en;
#pragma unroll 2
    for (int v4 = tid; v4 < nnpad4; v4 += PT2) {   // coalesced; L1/L2-resident
        const float4 e4 = en4[v4];
        DO_COL(e4.x);
        DO_COL(e4.y);
        DO_COL(e4.z);
        DO_COL(e4.w);
    }
#undef DO_COL
#undef Q4
#undef TERM

    float s = acc0 + acc1;
#pragma unroll
    for (int off = 32; off > 0; off >>= 1) s += __shfl_down(s, off, 64);
    if (lane == 0) wpart[gw] = (double)s;    // disjoint f64 write; no contention
}

// ---- Kernel 3: reduce wave partials + finalize ----------------------------
__global__ __launch_bounds__(1024)
void finalize_kernel(const int* __restrict__ cnts, const double* __restrict__ wpart,
                     int nwaves, float* __restrict__ out) {
    const int tid = threadIdx.x;
    double d = 0.0;
    for (int k = tid; k < nwaves; k += 1024) d += wpart[k];   // fixed order
#pragma unroll
    for (int off = 32; off > 0; off >>= 1) d += __shfl_down(d, off, 64);
    __shared__ double fsum[16];
    if ((tid & 63) == 0) fsum[tid >> 6] = d;
    __syncthreads();
    if (tid == 0) {
        double s = 0.0;
#pragma unroll
        for (int w = 0; w < 16; ++w) s += fsum[w];
        const double npairs = (double)cnts[0] * (double)cnts[1];
        out[0] = (npairs > 0.0) ? (float)(s * 0.6931471805599453 / npairs) : 0.0f;
    }
}

extern "C" void kernel_launch(void* const* d_in, const int* in_sizes, int n_in,
                              void* d_out, int out_size, void* d_ws, size_t ws_size,
                              hipStream_t stream) {
    const float* x  = (const float*)d_in[0];
    const int*   tg = (const int*)d_in[1];
    const int n = in_sizes[0];                 // 16384

    char* ws = (char*)d_ws;
    float*  pos_emp = (float*)(ws);            // 64 KB
    float*  neg_en  = (float*)(ws + 65536);    // 64 KB + pad
    int*    cnts    = (int*)(ws + 135168);     // 3 ints
    double* wpart   = (double*)(ws + 139264);  // 8192 doubles = 64 KB

    const int nblocks = (n + RB - 1) / RB;     // 1024 (worst case: all positive)
    const int nwaves  = nblocks * NW;          // 8192
    compact_kernel<<<1, CB, 0, stream>>>(x, tg, n, pos_emp, neg_en, cnts);
    pair_kernel<<<nblocks, PT2, 0, stream>>>(pos_emp, neg_en, cnts, wpart);
    finalize_kernel<<<1, 1024, 0, stream>>>(cnts, wpart, nwaves, (float*)d_out);
}

// Round 9
// 20.829 us; speedup vs baseline: 2.8091x; 1.0400x over previous
//
#include <hip/hip_runtime.h>

// RankingBCELoss: loss = (1/(n_pos*n_neg)) * sum_{p,n} log(1 + e^{x_n} * e^{-x_p})
// R9: 2 launches, no global compaction, no atomics, no hot-loop barriers.
//   K1 pair_masked: 512 blocks x 512 thr; block owns 32 raw rows. Wave 0
//     ballot-compacts the k positives' e^{-x} into LDS (one barrier, once),
//     k rounded up to 8 -> template<NQ=1..4> inner loop (static indices only).
//     Columns streamed masked from global (en = t==0 ? e^x : 0; L2-resident;
//     masked terms fma(0,emp,1)=1 absorbed free by the product-of-8 trick).
//     Per col x 8 rows: 8 fma + 7 mul + 1 v_log_f32. Wave partial -> wpart[4096].
//   K2 finalize: counts np/nn from tg directly + reduces wpart -> out.
// Lesson R4-R7 (measured): same-address device-scope atomics ~25ns serialized
// -> any per-block arrival pattern costs 10-50us. Structure avoids them entirely.

#define PT    512          // pair kernel threads (8 waves)
#define RB    32           // raw rows per block
#define NWAVE (PT / 64)

template<int NQ>
__device__ __forceinline__ float row_stream(const float* __restrict__ lds_emp,
                                            const float4* __restrict__ x4,
                                            const int4* __restrict__ t4,
                                            int n4, int tid) {
    float emp[NQ * 8];                       // template-static indices => registers
#pragma unroll
    for (int r = 0; r < NQ * 8; ++r) emp[r] = lds_emp[r];
    float acc[NQ];
#pragma unroll
    for (int q = 0; q < NQ; ++q) acc[q] = 0.f;

    auto do_col = [&](float xc, int tc) {
        const float en = (tc == 0) ? __expf(xc) : 0.f;   // masked negative
        // terms in [1, ~1e4]; product of 8 <= ~1e32 < 3.4e38: safe
#pragma unroll
        for (int q = 0; q < NQ; ++q) {
            float p0 = __builtin_fmaf(en, emp[q * 8 + 0], 1.f);
            p0 *= __builtin_fmaf(en, emp[q * 8 + 1], 1.f);
            p0 *= __builtin_fmaf(en, emp[q * 8 + 2], 1.f);
            p0 *= __builtin_fmaf(en, emp[q * 8 + 3], 1.f);
            float p1 = __builtin_fmaf(en, emp[q * 8 + 4], 1.f);
            p1 *= __builtin_fmaf(en, emp[q * 8 + 5], 1.f);
            p1 *= __builtin_fmaf(en, emp[q * 8 + 6], 1.f);
            p1 *= __builtin_fmaf(en, emp[q * 8 + 7], 1.f);
            acc[q] += __log2f(p0 * p1);      // 1 log per 8 real-or-masked rows
        }
    };

#pragma unroll 2
    for (int v = tid; v < n4; v += PT) {     // coalesced float4/int4; L2-resident
        const float4 xv = x4[v];
        const int4   tv = t4[v];
        do_col(xv.x, tv.x);
        do_col(xv.y, tv.y);
        do_col(xv.z, tv.z);
        do_col(xv.w, tv.w);
    }
    float s = 0.f;
#pragma unroll
    for (int q = 0; q < NQ; ++q) s += acc[q];
    return s;
}

__global__ __launch_bounds__(PT)
void pair_masked(const float* __restrict__ x, const int* __restrict__ tg,
                 int n, double* __restrict__ wpart) {
    __shared__ float lds_emp[RB];
    __shared__ int lds_k;
    const int bid = blockIdx.x, tid = threadIdx.x;
    const int lane = tid & 63, wid = tid >> 6;
    const int rbase = bid * RB;

    // ---- wave 0: ballot-compact this block's positive rows into LDS ----
    if (wid == 0) {
        float ex = 0.f; int isp = 0;
        if (lane < RB) {                     // 32 coalesced loads
            const int t = tg[rbase + lane];
            isp = (t == 1);
            if (isp) ex = __expf(-x[rbase + lane]);
        }
        const unsigned long long m = __ballot(isp);
        if (lane < RB) lds_emp[lane] = 0.f;  // zero-fill (same-wave order: write#2 wins)
        const int rank = (int)__popcll(m & ((1ull << lane) - 1ull));
        if (isp) lds_emp[rank] = ex;
        if (lane == 0) lds_k = (int)__popcll(m);
    }
    __syncthreads();                         // the ONLY barrier; outside all loops

    const int kq = (lds_k + 7) >> 3;         // 0..4 groups of 8 rows
    const int gw = bid * NWAVE + wid;
    if (kq == 0) {                           // block-uniform: no positives here
        if (lane == 0) wpart[gw] = 0.0;      // keep all slots written each call
        return;
    }

    const float4* x4 = (const float4*)x;
    const int4*   t4 = (const int4*)tg;
    const int n4 = n >> 2;
    float s;
    switch (kq) {                            // template dispatch: static indexing only
        case 1:  s = row_stream<1>(lds_emp, x4, t4, n4, tid); break;
        case 2:  s = row_stream<2>(lds_emp, x4, t4, n4, tid); break;
        case 3:  s = row_stream<3>(lds_emp, x4, t4, n4, tid); break;
        default: s = row_stream<4>(lds_emp, x4, t4, n4, tid); break;
    }

#pragma unroll
    for (int off = 32; off > 0; off >>= 1) s += __shfl_down(s, off, 64);
    if (lane == 0) wpart[gw] = (double)s;    // disjoint slot; no contention
}

__global__ __launch_bounds__(1024)
void finalize_kernel(const int* __restrict__ tg, int n,
                     const double* __restrict__ wpart, int nw,
                     float* __restrict__ out) {
    const int tid = threadIdx.x;
    // counts directly from tg (no dependency on a compact stage)
    int cp = 0, cn = 0;
    const int4* t4 = (const int4*)tg;
    for (int v = tid; v < (n >> 2); v += 1024) {
        const int4 t = t4[v];
        cp += (t.x == 1) + (t.y == 1) + (t.z == 1) + (t.w == 1);
        cn += (t.x == 0) + (t.y == 0) + (t.z == 0) + (t.w == 0);
    }
    double d = 0.0;
    for (int k = tid; k < nw; k += 1024) d += wpart[k];   // fixed order
    int c = cp | (cn << 16);
#pragma unroll
    for (int off = 32; off > 0; off >>= 1) {
        d += __shfl_down(d, off, 64);
        c += __shfl_down(c, off, 64);
    }
    __shared__ double fs[16];
    __shared__ int    fc[16];
    if ((tid & 63) == 0) { fs[tid >> 6] = d; fc[tid >> 6] = c; }
    __syncthreads();
    if (tid == 0) {
        double ssum = 0.0; int tot = 0;
#pragma unroll
        for (int w = 0; w < 16; ++w) { ssum += fs[w]; tot += fc[w]; }
        const int np = tot & 0xffff, nn = tot >> 16;
        const double npairs = (double)np * (double)nn;
        out[0] = (npairs > 0.0) ? (float)(ssum * 0.6931471805599453 / npairs) : 0.0f;
    }
}

extern "C" void kernel_launch(void* const* d_in, const int* in_sizes, int n_in,
                              void* d_out, int out_size, void* d_ws, size_t ws_size,
                              hipStream_t stream) {
    const float* x  = (const float*)d_in[0];
    const int*   tg = (const int*)d_in[1];
    const int n = in_sizes[0];                 // 16384

    double* wpart = (double*)d_ws;             // 4096 doubles = 32 KB
    const int nblocks = (n + RB - 1) / RB;     // 512
    const int nw = nblocks * NWAVE;            // 4096

    pair_masked<<<nblocks, PT, 0, stream>>>(x, tg, n, wpart);
    finalize_kernel<<<1, 1024, 0, stream>>>(tg, n, wpart, nw, (float*)d_out);
}